// Round 1
// baseline (1062.129 us; speedup 1.0000x reference)
//
#include <hip/hip_runtime.h>
#include <math.h>

#define BB 16
#define HH 12
#define NN 1025
#define DD 64
#define KK 256
#define NM1 1024
#define KP1 257

static __device__ __forceinline__ float flog(float t) { return logf(t + 1e-6f); }

#define MASK_VALUE (-1.7014117331926443e+38f) /* -FLT_MAX/2 */

// K1: scores[b,n] = sum_h attn[b,h,0,1+n] * ||value[b,h,1+n,:]||
// one block per (b,n); 12 waves (one per head), 64 lanes = D
__global__ void k_scores(const float* __restrict__ attn,
                         const float* __restrict__ value,
                         float* __restrict__ scores) {
    int bn = blockIdx.x;            // b*1024 + n
    int b  = bn >> 10;
    int n  = bn & 1023;
    int h    = threadIdx.x >> 6;
    int lane = threadIdx.x & 63;
    __shared__ float part[HH];
    size_t voff = ((size_t)(b * HH + h) * NN + (1 + n)) * DD + lane;
    float v = value[voff];
    float ss = v * v;
#pragma unroll
    for (int m = 32; m >= 1; m >>= 1) ss += __shfl_xor(ss, m, 64);
    if (lane == 0) {
        float cls = attn[((size_t)(b * HH + h) * NN) * NN + (1 + n)];
        part[h] = cls * sqrtf(ss);
    }
    __syncthreads();
    if (threadIdx.x == 0) {
        float s = 0.f;
        for (int i = 0; i < HH; i++) s += part[i];  // deterministic h-order
        scores[bn] = s;
    }
}

// K2: pseudo_logits[b,n] = log(scores/(sum+eps)+eps), masked. one block per b.
__global__ void k_pseudo(const float* __restrict__ scores,
                         const int* __restrict__ mask,
                         float* __restrict__ pl) {
    int b = blockIdx.x;
    int n = threadIdx.x;            // 1024 threads
    __shared__ float red[1024];
    float sc = scores[b * NM1 + n];
    red[n] = sc;
    __syncthreads();
    for (int st = 512; st >= 1; st >>= 1) {
        if (n < st) red[n] += red[n + st];
        __syncthreads();
    }
    float sum = red[0];
    float p = logf(sc / (sum + 1e-6f) + 1e-6f);
    if (mask[b * NN + 1 + n] == 0) p = MASK_VALUE;
    pl[b * NM1 + n] = p;
}

// K3: sampled[b,k] = argmax_n(pl[b,n] + gumbel(b,k,n)) + 1. one wave per (b,k).
__global__ void k_sample(const float* __restrict__ pl,
                         const float* __restrict__ gn,
                         int* __restrict__ sampled) {
    int wave = (blockIdx.x << 2) + (threadIdx.x >> 6);   // b*K + k
    int lane = threadIdx.x & 63;
    int b = wave >> 8;
    const float* plb = pl + b * NM1;
    const float* g = gn + (size_t)wave * NM1;
    float best = -3.4e38f;
    int bidx = 0;
#pragma unroll
    for (int i = 0; i < 16; i++) {
        int n = i * 64 + lane;
        float u = g[n];
        float gv = -logf(-logf(u + 1e-6f) + 1e-6f);
        float lv = plb[n] + gv;
        if (lv > best) { best = lv; bidx = n; }   // strict > keeps first idx in-lane
    }
    for (int m = 1; m < 64; m <<= 1) {
        float ov = __shfl_xor(best, m, 64);
        int   oi = __shfl_xor(bidx, m, 64);
        if (ov > best || (ov == best && oi < bidx)) { best = ov; bidx = oi; }
    }
    if (lane == 0) sampled[wave] = bidx + 1;
}

// K4: per-b sort/dedupe/sort, emit ids (int + float) and mask. one block per b, 256 thr.
__global__ void k_dedupe(const int* __restrict__ sampled,
                         int* __restrict__ ids_int,
                         float* __restrict__ out_mask,
                         float* __restrict__ out_ids) {
    int b = blockIdx.x;
    int t = threadIdx.x;
    __shared__ int s[KK];
    __shared__ int srt[KK];
    __shared__ int w[KK];
    __shared__ int uniq[KK];
    s[t] = sampled[b * KK + t];
    __syncthreads();
    int v = s[t];
    int r = 0;
    for (int j = 0; j < KK; j++) {
        int sj = s[j];
        r += (sj < v) || (sj == v && j < t);   // stable rank sort
    }
    srt[r] = v;
    __syncthreads();
    int wv = (t > 0 && srt[t] == srt[t - 1]) ? 0 : srt[t];
    w[t] = wv;
    __syncthreads();
    int r2 = 0;
    for (int j = 0; j < KK; j++) {
        int wj = w[j];
        r2 += (wj < wv) || (wj == wv && j < t);
    }
    uniq[r2] = wv;
    __syncthreads();
    int idv = uniq[t];
    ids_int[b * KP1 + 1 + t] = idv;
    out_ids[b * KP1 + 1 + t] = (float)idv;
    out_mask[b * KP1 + 1 + t] = idv != 0 ? 1.0f : 0.0f;
    if (t == 0) {
        ids_int[b * KP1] = 0;
        out_ids[b * KP1] = 0.0f;
        out_mask[b * KP1] = 1.0f;
    }
}

// K5: new_attn[b,h,j,:] = attn[b,h,ids[b,j],:]. one block per output row.
__global__ void k_gather(const float* __restrict__ attn,
                         const int* __restrict__ ids_int,
                         float* __restrict__ out) {
    int row = blockIdx.x;            // (b*H + h)*257 + j
    int j  = row % KP1;
    int bh = row / KP1;
    int b  = bh / HH;
    int id = ids_int[b * KP1 + j];
    const float* src = attn + ((size_t)bh * NN + id) * NN;
    float* dst = out + (size_t)row * NN;
    for (int c = threadIdx.x; c < NN; c += blockDim.x) dst[c] = src[c];
}

extern "C" void kernel_launch(void* const* d_in, const int* in_sizes, int n_in,
                              void* d_out, int out_size, void* d_ws, size_t ws_size,
                              hipStream_t stream) {
    const float* attn  = (const float*)d_in[0];
    const float* value = (const float*)d_in[1];
    const float* gn    = (const float*)d_in[2];
    const int*   mask  = (const int*)d_in[3];

    // workspace layout
    float* scores = (float*)d_ws;                 // B*1024
    float* pl     = scores + BB * NM1;            // B*1024
    int* sampled  = (int*)(pl + BB * NM1);        // B*K
    int* ids_int  = sampled + BB * KK;            // B*257

    // output layout (all float32, concatenated)
    float* out_attn = (float*)d_out;                               // B*H*257*1025
    float* out_mask = out_attn + (size_t)BB * HH * KP1 * NN;       // B*257
    float* out_ids  = out_mask + BB * KP1;                         // B*257

    k_scores<<<BB * NM1, HH * 64, 0, stream>>>(attn, value, scores);
    k_pseudo<<<BB, 1024, 0, stream>>>(scores, mask, pl);
    k_sample<<<BB * KK / 4, 256, 0, stream>>>(pl, gn, sampled);
    k_dedupe<<<BB, 256, 0, stream>>>(sampled, ids_int, out_mask, out_ids);
    k_gather<<<BB * HH * KP1, 256, 0, stream>>>(attn, ids_int, out_attn);
}

// Round 3
// 1051.486 us; speedup vs baseline: 1.0101x; 1.0101x over previous
//
#include <hip/hip_runtime.h>
#include <math.h>

#define BB 16
#define HH 12
#define NN 1025
#define DD 64
#define KK 256
#define NM1 1024
#define KP1 257

#define MASK_VALUE (-1.7014117331926443e+38f) /* -FLT_MAX/2 */

typedef float vfloat4 __attribute__((ext_vector_type(4)));

// K1: scores[b,n] = sum_h attn[b,h,0,1+n] * ||value[b,h,1+n,:]||
// one block per (b,n); 12 waves (one per head), 64 lanes = D
__global__ void k_scores(const float* __restrict__ attn,
                         const float* __restrict__ value,
                         float* __restrict__ scores) {
    int bn = blockIdx.x;            // b*1024 + n
    int b  = bn >> 10;
    int n  = bn & 1023;
    int h    = threadIdx.x >> 6;
    int lane = threadIdx.x & 63;
    __shared__ float part[HH];
    size_t voff = ((size_t)(b * HH + h) * NN + (1 + n)) * DD + lane;
    float v = value[voff];
    float ss = v * v;
#pragma unroll
    for (int m = 32; m >= 1; m >>= 1) ss += __shfl_xor(ss, m, 64);
    if (lane == 0) {
        float cls = attn[((size_t)(b * HH + h) * NN) * NN + (1 + n)];
        part[h] = cls * sqrtf(ss);
    }
    __syncthreads();
    if (threadIdx.x == 0) {
        float s = 0.f;
        for (int i = 0; i < HH; i++) s += part[i];  // deterministic h-order
        scores[bn] = s;
    }
}

// K2: pseudo_logits[b,n] = log(scores/(sum+eps)+eps), masked. one block per b.
__global__ void k_pseudo(const float* __restrict__ scores,
                         const int* __restrict__ mask,
                         float* __restrict__ pl) {
    int b = blockIdx.x;
    int n = threadIdx.x;            // 1024 threads
    __shared__ float red[1024];
    float sc = scores[b * NM1 + n];
    red[n] = sc;
    __syncthreads();
    for (int st = 512; st >= 1; st >>= 1) {
        if (n < st) red[n] += red[n + st];
        __syncthreads();
    }
    float sum = red[0];
    float p = logf(sc / (sum + 1e-6f) + 1e-6f);
    if (mask[b * NN + 1 + n] == 0) p = MASK_VALUE;
    pl[b * NM1 + n] = p;
}

// K3: sampled[b,k] = argmax_n(pl[b,n] + gumbel(b,k,n)) + 1. one wave per (b,k).
// Math kept bit-identical to the reference path (passed absmax 0.0).
__global__ void k_sample(const float* __restrict__ pl,
                         const float* __restrict__ gn,
                         int* __restrict__ sampled) {
    int wave = (blockIdx.x << 2) + (threadIdx.x >> 6);   // b*K + k
    int lane = threadIdx.x & 63;
    int b = wave >> 8;
    const float* plb = pl + b * NM1;
    const float* g = gn + (size_t)wave * NM1;
    float best = -3.4e38f;
    int bidx = 0x7fffffff;
#pragma unroll
    for (int i = 0; i < 16; i++) {
        int n = i * 64 + lane;
        float u = g[n];
        float gv = -logf(-logf(u + 1e-6f) + 1e-6f);
        float lv = plb[n] + gv;
        if (lv > best || (lv == best && n < bidx)) { best = lv; bidx = n; }
    }
    for (int m = 1; m < 64; m <<= 1) {
        float ov = __shfl_xor(best, m, 64);
        int   oi = __shfl_xor(bidx, m, 64);
        if (ov > best || (ov == best && oi < bidx)) { best = ov; bidx = oi; }
    }
    if (lane == 0) sampled[wave] = bidx + 1;
}

// K4: per-b sort/dedupe/sort, emit ids (int + float) and mask. one block per b, 256 thr.
__global__ void k_dedupe(const int* __restrict__ sampled,
                         int* __restrict__ ids_int,
                         float* __restrict__ out_mask,
                         float* __restrict__ out_ids) {
    int b = blockIdx.x;
    int t = threadIdx.x;
    __shared__ int s[KK];
    __shared__ int srt[KK];
    __shared__ int w[KK];
    __shared__ int uniq[KK];
    s[t] = sampled[b * KK + t];
    __syncthreads();
    int v = s[t];
    int r = 0;
    for (int j = 0; j < KK; j++) {
        int sj = s[j];
        r += (sj < v) || (sj == v && j < t);   // stable rank sort
    }
    srt[r] = v;
    __syncthreads();
    int wv = (t > 0 && srt[t] == srt[t - 1]) ? 0 : srt[t];
    w[t] = wv;
    __syncthreads();
    int r2 = 0;
    for (int j = 0; j < KK; j++) {
        int wj = w[j];
        r2 += (wj < wv) || (wj == wv && j < t);
    }
    uniq[r2] = wv;
    __syncthreads();
    int idv = uniq[t];
    ids_int[b * KP1 + 1 + t] = idv;
    out_ids[b * KP1 + 1 + t] = (float)idv;
    out_mask[b * KP1 + 1 + t] = idv != 0 ? 1.0f : 0.0f;
    if (t == 0) {
        ids_int[b * KP1] = 0;
        out_ids[b * KP1] = 0.0f;
        out_mask[b * KP1] = 1.0f;
    }
}

// K5: new_attn[b,h,j,:] = attn[b,h,ids[b,j],:]. one block per output row.
// float4 stores (dst-aligned via peel) + nontemporal streaming writes.
__global__ void k_gather(const float* __restrict__ attn,
                         const int* __restrict__ ids_int,
                         float* __restrict__ out) {
    int row = blockIdx.x;            // (b*H + h)*257 + j
    int j  = row % KP1;
    int bh = row / KP1;
    int b  = bh / HH;
    int id = ids_int[b * KP1 + j];
    const float* src = attn + ((size_t)bh * NN + id) * NN;
    float* dst = out + (size_t)row * NN;
    int t = threadIdx.x;             // 256

    int mis  = (int)(((size_t)row * NN) & 3);  // dst element offset mod 4
    int head = (4 - mis) & 3;                  // scalar floats before 16B-aligned region
    if (t < head) dst[t] = src[t];

    int remaining = NN - head;
    int nvec = remaining >> 2;                 // 255 or 256 float4s
    const float* s2 = src + head;
    vfloat4* d4 = (vfloat4*)(dst + head);
    for (int v = t; v < nvec; v += 256) {
        vfloat4 val;
        val.x = s2[4 * v + 0];
        val.y = s2[4 * v + 1];
        val.z = s2[4 * v + 2];
        val.w = s2[4 * v + 3];
        __builtin_nontemporal_store(val, &d4[v]);
    }

    int done = head + (nvec << 2);
    int tail = NN - done;                      // 0..3
    if (t < tail) dst[done + t] = src[done + t];
}

extern "C" void kernel_launch(void* const* d_in, const int* in_sizes, int n_in,
                              void* d_out, int out_size, void* d_ws, size_t ws_size,
                              hipStream_t stream) {
    const float* attn  = (const float*)d_in[0];
    const float* value = (const float*)d_in[1];
    const float* gn    = (const float*)d_in[2];
    const int*   mask  = (const int*)d_in[3];

    // workspace layout
    float* scores = (float*)d_ws;                 // B*1024
    float* pl     = scores + BB * NM1;            // B*1024
    int* sampled  = (int*)(pl + BB * NM1);        // B*K
    int* ids_int  = sampled + BB * KK;            // B*257

    // output layout (all float32, concatenated)
    float* out_attn = (float*)d_out;                               // B*H*257*1025
    float* out_mask = out_attn + (size_t)BB * HH * KP1 * NN;       // B*257
    float* out_ids  = out_mask + BB * KP1;                         // B*257

    k_scores<<<BB * NM1, HH * 64, 0, stream>>>(attn, value, scores);
    k_pseudo<<<BB, 1024, 0, stream>>>(scores, mask, pl);
    k_sample<<<BB * KK / 4, 256, 0, stream>>>(pl, gn, sampled);
    k_dedupe<<<BB, 256, 0, stream>>>(sampled, ids_int, out_mask, out_ids);
    k_gather<<<BB * HH * KP1, 256, 0, stream>>>(attn, ids_int, out_attn);
}